// Round 4
// baseline (668.340 us; speedup 1.0000x reference)
//
#include <hip/hip_runtime.h>

typedef unsigned short u16;
typedef unsigned int u32;
typedef _Float16 f16;
typedef __attribute__((ext_vector_type(8))) _Float16 half8;
typedef __attribute__((ext_vector_type(4))) float floatx4;

#define HWSZ 40000
#define NB 40

__device__ __forceinline__ u16 f2h(float f) {
  union { f16 h; u16 u; } c; c.h = (f16)f; return c.u;
}

// ---------------- K0: weight fp32 -> fp16 cast + rel table ----------------
__global__ __launch_bounds__(256) void k_tw(
    const float* __restrict__ Wmap, const float* __restrict__ Wq,
    const float* __restrict__ Wk, const float* __restrict__ Wv,
    const float* __restrict__ relh, const float* __restrict__ relw,
    u16* __restrict__ wmapB, u16* __restrict__ wqB,
    u16* __restrict__ wkB, u16* __restrict__ wvB, u16* __restrict__ relB) {
  int which = blockIdx.y;
  int idx = blockIdx.x * 256 + threadIdx.x;
  if (which == 4) {
    if (idx < 8192) {
      int j = idx >> 6, d = idx & 63;
      float val = 0.f;
      if (j < 121) {
        int ky = j / 11, kx = j - ky * 11;
        val = (d < 32) ? relh[ky * 32 + d] : relw[kx * 32 + (d - 32)];
      }
      relB[idx] = f2h(val);
    }
    return;
  }
  const float* src; u16* dst; int n;
  if (which == 0)      { src = Wmap; dst = wmapB; n = 131072; }
  else if (which == 1) { src = Wq;   dst = wqB;   n = 65536; }
  else if (which == 2) { src = Wk;   dst = wkB;   n = 65536; }
  else                 { src = Wv;   dst = wvB;   n = 65536; }
  if (idx < n) dst[idx] = f2h(src[idx]);
}

// ---------------- K1a: n_aux = relu(W_map @ [noisy;aux] + b), f16 MFMA ----------------
// output fp16 pixel-major [b][hw][256]. Output staging aliases xs (LDS 50->33 KB, 4 blk/CU).
__global__ __launch_bounds__(256) void k_naux(
    const float* __restrict__ noisy, const float* __restrict__ aux,
    const u16* __restrict__ wmapB, const float* __restrict__ bmap,
    u16* __restrict__ naux) {
  __shared__ __align__(16) u16 xs[32 * 520];   // input staging; reused as output staging
  int t = threadIdx.x;
  int bi = blockIdx.y;
  int hw0 = blockIdx.x * 32;
  int wave = t >> 6, lane = t & 63;
  int quad = lane >> 4, l16 = lane & 15;

#pragma unroll
  for (int m = 0; m < 16; ++m) {
    int idx = m * 256 + t;
    int ci = idx >> 3, sub = idx & 7;
    const float* src = (ci < 256 ? noisy + (size_t)(bi * 256 + ci) * HWSZ
                                 : aux + (size_t)(bi * 256 + (ci - 256)) * HWSZ) + hw0 + sub * 4;
    float4 vx = *(const float4*)src;
    xs[(sub * 4 + 0) * 520 + ci] = f2h(vx.x);
    xs[(sub * 4 + 1) * 520 + ci] = f2h(vx.y);
    xs[(sub * 4 + 2) * 520 + ci] = f2h(vx.z);
    xs[(sub * 4 + 3) * 520 + ci] = f2h(vx.w);
  }
  __syncthreads();

  floatx4 acc[4][2];
#pragma unroll
  for (int mt = 0; mt < 4; ++mt)
#pragma unroll
    for (int nt = 0; nt < 2; ++nt) acc[mt][nt] = (floatx4){0.f, 0.f, 0.f, 0.f};

  const u16* wbase = wmapB + (size_t)(wave * 64 + l16) * 512 + quad * 8;
#pragma unroll 4
  for (int ks = 0; ks < 16; ++ks) {
    half8 a[4], b[2];
#pragma unroll
    for (int mt = 0; mt < 4; ++mt)
      a[mt] = *(const half8*)(wbase + mt * 16 * 512 + ks * 32);
#pragma unroll
    for (int nt = 0; nt < 2; ++nt)
      b[nt] = *(const half8*)(&xs[(nt * 16 + l16) * 520 + ks * 32 + quad * 8]);
#pragma unroll
    for (int mt = 0; mt < 4; ++mt)
#pragma unroll
      for (int nt = 0; nt < 2; ++nt)
        acc[mt][nt] = __builtin_amdgcn_mfma_f32_16x16x32_f16(a[mt], b[nt], acc[mt][nt], 0, 0, 0);
  }
  __syncthreads();   // all xs reads done -> safe to reuse xs for output staging

#pragma unroll
  for (int mt = 0; mt < 4; ++mt) {
#pragma unroll
    for (int r = 0; r < 4; ++r) {
      int co = wave * 64 + mt * 16 + quad * 4 + r;
      float bv = bmap[co];
#pragma unroll
      for (int nt = 0; nt < 2; ++nt) {
        int px = nt * 16 + l16;
        xs[px * 264 + co] = f2h(fmaxf(acc[mt][nt][r] + bv, 0.f));
      }
    }
  }
  __syncthreads();

#pragma unroll
  for (int m = 0; m < 4; ++m) {
    int idx = m * 256 + t;
    int px = idx >> 5, sub = idx & 31;
    *(uint4*)(naux + ((size_t)bi * HWSZ + hw0 + px) * 256 + sub * 8) =
        *(const uint4*)(&xs[px * 264 + sub * 8]);
  }
}

// ---------------- K1b: q,k from naux; v from noisy — f16 MFMA ----------------
__global__ __launch_bounds__(256) void k_qkv(
    const u16* __restrict__ naux, const float* __restrict__ noisy,
    const u16* __restrict__ wqB, const u16* __restrict__ wkB,
    const u16* __restrict__ wvB,
    u16* __restrict__ q, u16* __restrict__ k, u16* __restrict__ v) {
  __shared__ __align__(16) u16 xs[32 * 264];
  __shared__ __align__(16) u16 os[32 * 264];
  int t = threadIdx.x;
  int bi = blockIdx.y;
  int hw0 = blockIdx.x * 32;
  int wave = t >> 6, lane = t & 63;
  int quad = lane >> 4, l16 = lane & 15;

#pragma unroll
  for (int m = 0; m < 4; ++m) {
    int idx = m * 256 + t;
    int px = idx >> 5, sub = idx & 31;
    *(uint4*)(&xs[px * 264 + sub * 8]) =
        *(const uint4*)(naux + ((size_t)bi * HWSZ + hw0 + px) * 256 + sub * 8);
  }
  __syncthreads();

#pragma unroll 1
  for (int pass = 0; pass < 2; ++pass) {
    const u16* wb = (pass == 0 ? wqB : wkB) + (size_t)(wave * 64 + l16) * 256 + quad * 8;
    floatx4 acc[4][2];
#pragma unroll
    for (int mt = 0; mt < 4; ++mt)
#pragma unroll
      for (int nt = 0; nt < 2; ++nt) acc[mt][nt] = (floatx4){0.f, 0.f, 0.f, 0.f};
#pragma unroll 4
    for (int ks = 0; ks < 8; ++ks) {
      half8 a[4], b[2];
#pragma unroll
      for (int mt = 0; mt < 4; ++mt)
        a[mt] = *(const half8*)(wb + mt * 16 * 256 + ks * 32);
#pragma unroll
      for (int nt = 0; nt < 2; ++nt)
        b[nt] = *(const half8*)(&xs[(nt * 16 + l16) * 264 + ks * 32 + quad * 8]);
#pragma unroll
      for (int mt = 0; mt < 4; ++mt)
#pragma unroll
        for (int nt = 0; nt < 2; ++nt)
          acc[mt][nt] = __builtin_amdgcn_mfma_f32_16x16x32_f16(a[mt], b[nt], acc[mt][nt], 0, 0, 0);
    }
    float scale = pass == 0 ? 0.125f : 1.f;
#pragma unroll
    for (int mt = 0; mt < 4; ++mt)
#pragma unroll
      for (int r = 0; r < 4; ++r) {
        int co = wave * 64 + mt * 16 + quad * 4 + r;
#pragma unroll
        for (int nt = 0; nt < 2; ++nt)
          os[(nt * 16 + l16) * 264 + co] = f2h(acc[mt][nt][r] * scale);
      }
    __syncthreads();
    u16* dst = pass == 0 ? q : k;
#pragma unroll
    for (int m = 0; m < 4; ++m) {
      int idx = m * 256 + t;
      int px = idx >> 5, sub = idx & 31;
      *(uint4*)(dst + ((size_t)bi * HWSZ + hw0 + px) * 256 + sub * 8) =
          *(const uint4*)(&os[px * 264 + sub * 8]);
    }
    __syncthreads();
  }

#pragma unroll
  for (int m = 0; m < 8; ++m) {
    int idx = m * 256 + t;
    int ci = idx >> 3, sub = idx & 7;
    const float* src = noisy + (size_t)(bi * 256 + ci) * HWSZ + hw0 + sub * 4;
    float4 vx = *(const float4*)src;
    xs[(sub * 4 + 0) * 264 + ci] = f2h(vx.x);
    xs[(sub * 4 + 1) * 264 + ci] = f2h(vx.y);
    xs[(sub * 4 + 2) * 264 + ci] = f2h(vx.z);
    xs[(sub * 4 + 3) * 264 + ci] = f2h(vx.w);
  }
  __syncthreads();
  {
    const u16* wb = wvB + (size_t)(wave * 64 + l16) * 256 + quad * 8;
    floatx4 acc[4][2];
#pragma unroll
    for (int mt = 0; mt < 4; ++mt)
#pragma unroll
      for (int nt = 0; nt < 2; ++nt) acc[mt][nt] = (floatx4){0.f, 0.f, 0.f, 0.f};
#pragma unroll 4
    for (int ks = 0; ks < 8; ++ks) {
      half8 a[4], b[2];
#pragma unroll
      for (int mt = 0; mt < 4; ++mt)
        a[mt] = *(const half8*)(wb + mt * 16 * 256 + ks * 32);
#pragma unroll
      for (int nt = 0; nt < 2; ++nt)
        b[nt] = *(const half8*)(&xs[(nt * 16 + l16) * 264 + ks * 32 + quad * 8]);
#pragma unroll
      for (int mt = 0; mt < 4; ++mt)
#pragma unroll
        for (int nt = 0; nt < 2; ++nt)
          acc[mt][nt] = __builtin_amdgcn_mfma_f32_16x16x32_f16(a[mt], b[nt], acc[mt][nt], 0, 0, 0);
    }
#pragma unroll
    for (int mt = 0; mt < 4; ++mt)
#pragma unroll
      for (int r = 0; r < 4; ++r) {
        int co = wave * 64 + mt * 16 + quad * 4 + r;
#pragma unroll
        for (int nt = 0; nt < 2; ++nt)
          os[(nt * 16 + l16) * 264 + co] = f2h(acc[mt][nt][r]);
      }
    __syncthreads();
#pragma unroll
    for (int m = 0; m < 4; ++m) {
      int idx = m * 256 + t;
      int px = idx >> 5, sub = idx & 31;
      *(uint4*)(v + ((size_t)bi * HWSZ + hw0 + px) * 256 + sub * 8) =
          *(const uint4*)(&os[px * 264 + sub * 8]);
    }
  }
}

// ---------------- K2: halo block attention — d-split V (LDS 16KB -> 10 blk/CU) ----------------
// vt/pf positions XOR-swizzled (p8 ^= ((p8>>6)&3)<<4) on both write and read:
// staging write conflicts 16-way -> 4-way; b128 reads stay 16B-aligned, 2-way (free).
__global__ __launch_bounds__(64) void k_attn(
    const u16* __restrict__ q, const u16* __restrict__ k,
    const u16* __restrict__ v, const u16* __restrict__ relB,
    u16* __restrict__ o16) {
  __shared__ __align__(16) u16 vt[8 * 512];    // one d-half of V^T frags (8 KB)
  __shared__ __align__(16) u16 pf[8 * 512];    // P frags (8 KB)

  int t = threadIdx.x;           // single wave
  int bb = blockIdx.z;
  int head = blockIdx.y;
  int bid = blockIdx.x;
  int sb = (bid & 7) * 200 + (bid >> 3);       // XCD-chunked bijective swizzle
  int by = sb / NB, bx = sb % NB;
  int l16 = t & 15, quad = t >> 4;
  int hi = l16 >> 3, lowl = l16 & 7;

  const size_t hbase = (size_t)bb * HWSZ;
  const int hoff = head * 64;

  // ---- stage V^T half0 (d 0..31) + prefetch half1 (d 32..63) into regs ----
  uint4 r1[8];
#pragma unroll
  for (int it = 0; it < 8; ++it) {
    int idx = it * 64 + t;       // 0..511: j x c8p(4 chunks of d-half)
    int j = idx >> 2, c8p = idx & 3;
    int jc = min(j, 120);
    int ky = jc / 11, kx = jc - ky * 11;
    int y = by * 5 - 3 + ky, x = bx * 5 - 3 + kx;
    bool inb = (j <= 120) && (y >= 0) && (y < 200) && (x >= 0) && (x < 200);
    int yc = min(max(y, 0), 199), xc = min(max(x, 0), 199);
    const u16* vb = v + (hbase + yc * 200 + xc) * 256 + hoff;
    uint4 raw0 = *(const uint4*)(vb + c8p * 8);
    uint4 raw1 = *(const uint4*)(vb + 32 + c8p * 8);
    if (!inb) { raw0 = (uint4){0, 0, 0, 0}; raw1 = (uint4){0, 0, 0, 0}; }
    r1[it] = raw1;
    int frag = (c8p >> 1) * 4 + (j >> 5);
    int tb = ((j >> 3) & 3) * 16 + (c8p & 1) * 8;
    int msk = ((tb >> 3) & 3) << 4;
    int e = j & 7;
    u32 w[4] = {raw0.x, raw0.y, raw0.z, raw0.w};
#pragma unroll
    for (int i = 0; i < 8; ++i) {
      u16 val = (u16)((i & 1) ? (w[i >> 1] >> 16) : (w[i >> 1] & 0xffffu));
      vt[frag * 512 + (((tb + i) * 8) ^ msk) + e] = val;
    }
  }

  // ---- Q a-frags from global ----
  half8 aq[2][2];
#pragma unroll
  for (int mt = 0; mt < 2; ++mt) {
    int i = min(mt * 16 + l16, 24);
    int y = by * 5 + i / 5, x = bx * 5 + i % 5;
    const u16* qb = q + (hbase + y * 200 + x) * 256 + hoff;
#pragma unroll
    for (int ks = 0; ks < 2; ++ks)
      aq[mt][ks] = *(const half8*)(qb + ks * 32 + quad * 8);
  }

  // ---- S = Q.K^T + Q.Rel^T ----
  floatx4 acc[2][8];
#pragma unroll
  for (int mt = 0; mt < 2; ++mt)
#pragma unroll
    for (int nt = 0; nt < 8; ++nt) acc[mt][nt] = (floatx4){0.f, 0.f, 0.f, 0.f};

#pragma unroll 2
  for (int nt = 0; nt < 8; ++nt) {
    int j = nt * 16 + l16;
    int jc = min(j, 120);
    int ky = jc / 11, kx = jc - ky * 11;
    int y = by * 5 - 3 + ky, x = bx * 5 - 3 + kx;
    bool inb = (y >= 0) && (y < 200) && (x >= 0) && (x < 200);
    int yc = min(max(y, 0), 199), xc = min(max(x, 0), 199);
    const u16* kb = k + (hbase + yc * 200 + xc) * 256 + hoff;
    const u16* rb = relB + jc * 64;
#pragma unroll
    for (int ks = 0; ks < 2; ++ks) {
      uint4 raw = *(const uint4*)(kb + ks * 32 + quad * 8);
      if (!inb) raw = (uint4){0, 0, 0, 0};
      union { uint4 u; half8 h; } kc; kc.u = raw;
      half8 rl = *(const half8*)(rb + ks * 32 + quad * 8);
#pragma unroll
      for (int mt = 0; mt < 2; ++mt) {
        acc[mt][nt] = __builtin_amdgcn_mfma_f32_16x16x32_f16(aq[mt][ks], kc.h, acc[mt][nt], 0, 0, 0);
        acc[mt][nt] = __builtin_amdgcn_mfma_f32_16x16x32_f16(aq[mt][ks], rl, acc[mt][nt], 0, 0, 0);
      }
    }
  }
  __syncthreads();  // vt half0 staged

  // ---- softmax in registers + write P frags (swizzled) ----
  float rinv[2][4];
#pragma unroll
  for (int mt = 0; mt < 2; ++mt) {
#pragma unroll
    for (int r = 0; r < 4; ++r) {
      float vmax = acc[mt][0][r];
#pragma unroll
      for (int nt = 1; nt < 7; ++nt) vmax = fmaxf(vmax, acc[mt][nt][r]);
      float x7 = (l16 < 9) ? acc[mt][7][r] : -INFINITY;
      vmax = fmaxf(vmax, x7);
#pragma unroll
      for (int off = 1; off < 16; off <<= 1)
        vmax = fmaxf(vmax, __shfl_xor(vmax, off, 16));
      float es[8], sum = 0.f;
#pragma unroll
      for (int nt = 0; nt < 7; ++nt) { es[nt] = __expf(acc[mt][nt][r] - vmax); sum += es[nt]; }
      es[7] = (l16 < 9) ? __expf(acc[mt][7][r] - vmax) : 0.f;
      sum += es[7];
#pragma unroll
      for (int off = 1; off < 16; off <<= 1)
        sum += __shfl_xor(sum, off, 16);
      rinv[mt][r] = 1.f / sum;
      int arow = quad * 4 + r;
#pragma unroll
      for (int nt = 0; nt < 8; ++nt) {
        int T2 = ((nt & 1) * 2 + hi) * 16 + arow;
        pf[(mt * 4 + (nt >> 1)) * 512 + ((T2 * 8) ^ (((T2 >> 3) & 3) << 4)) + lowl] = f2h(es[nt]);
      }
    }
  }
  __syncthreads();  // pf written

  // ---- O = P.V, d-half 0 (nd 0,1) ----
  int swzr = (t * 8) ^ (((t >> 3) & 3) << 4);
  floatx4 o[2][4];
#pragma unroll
  for (int mt = 0; mt < 2; ++mt)
#pragma unroll
    for (int nd = 0; nd < 4; ++nd) o[mt][nd] = (floatx4){0.f, 0.f, 0.f, 0.f};
#pragma unroll
  for (int ks = 0; ks < 4; ++ks) {
    half8 a[2], b[2];
#pragma unroll
    for (int mt = 0; mt < 2; ++mt)
      a[mt] = *(const half8*)(&pf[(mt * 4 + ks) * 512 + swzr]);
#pragma unroll
    for (int ndl = 0; ndl < 2; ++ndl)
      b[ndl] = *(const half8*)(&vt[(ndl * 4 + ks) * 512 + swzr]);
#pragma unroll
    for (int mt = 0; mt < 2; ++mt)
#pragma unroll
      for (int ndl = 0; ndl < 2; ++ndl)
        o[mt][ndl] = __builtin_amdgcn_mfma_f32_16x16x32_f16(a[mt], b[ndl], o[mt][ndl], 0, 0, 0);
  }
  __syncthreads();  // half0 reads done

  // ---- write V^T half1 from regs ----
#pragma unroll
  for (int it = 0; it < 8; ++it) {
    int idx = it * 64 + t;
    int j = idx >> 2, c8p = idx & 3;
    int frag = (c8p >> 1) * 4 + (j >> 5);
    int tb = ((j >> 3) & 3) * 16 + (c8p & 1) * 8;
    int msk = ((tb >> 3) & 3) << 4;
    int e = j & 7;
    u32 w[4] = {r1[it].x, r1[it].y, r1[it].z, r1[it].w};
#pragma unroll
    for (int i = 0; i < 8; ++i) {
      u16 val = (u16)((i & 1) ? (w[i >> 1] >> 16) : (w[i >> 1] & 0xffffu));
      vt[frag * 512 + (((tb + i) * 8) ^ msk) + e] = val;
    }
  }
  __syncthreads();  // half1 staged

  // ---- O = P.V, d-half 1 (nd 2,3) ----
#pragma unroll
  for (int ks = 0; ks < 4; ++ks) {
    half8 a[2], b[2];
#pragma unroll
    for (int mt = 0; mt < 2; ++mt)
      a[mt] = *(const half8*)(&pf[(mt * 4 + ks) * 512 + swzr]);
#pragma unroll
    for (int ndl = 0; ndl < 2; ++ndl)
      b[ndl] = *(const half8*)(&vt[(ndl * 4 + ks) * 512 + swzr]);
#pragma unroll
    for (int mt = 0; mt < 2; ++mt)
#pragma unroll
      for (int ndl = 0; ndl < 2; ++ndl)
        o[mt][2 + ndl] = __builtin_amdgcn_mfma_f32_16x16x32_f16(a[mt], b[ndl], o[mt][2 + ndl], 0, 0, 0);
  }

  // ---- epilogue: scale by 1/sum, store fp16 pixel-major (32B segments) ----
#pragma unroll
  for (int mt = 0; mt < 2; ++mt) {
#pragma unroll
    for (int r = 0; r < 4; ++r) {
      int i = mt * 16 + quad * 4 + r;
      if (i < 25) {
        int y = by * 5 + i / 5, x = bx * 5 + i % 5;
        float rs = rinv[mt][r];
        u16* ob = o16 + (hbase + y * 200 + x) * 256 + hoff;
#pragma unroll
        for (int nd = 0; nd < 4; ++nd)
          ob[nd * 16 + l16] = f2h(o[mt][nd][r] * rs);
      }
    }
  }
}

// ---------------- K3: transpose o16 [b][hw][256] f16 -> out [b][c][h][w] f32 ----------------
__global__ __launch_bounds__(256) void k_out(
    const u16* __restrict__ o16, float* __restrict__ out) {
  __shared__ __align__(16) u16 xs[64 * 264];
  int t = threadIdx.x;
  int bi = blockIdx.y;
  int hw0 = blockIdx.x * 64;
#pragma unroll
  for (int m = 0; m < 8; ++m) {
    int idx = m * 256 + t;
    int px = idx >> 5, sub = idx & 31;
    int sw = sub ^ ((px >> 2) & 7);
    *(uint4*)(&xs[px * 264 + sw * 8]) =
        *(const uint4*)(o16 + ((size_t)bi * HWSZ + hw0 + px) * 256 + sub * 8);
  }
  __syncthreads();
#pragma unroll
  for (int m = 0; m < 16; ++m) {
    int idx = m * 256 + t;
    int c = idx >> 4, g = idx & 15;
    int C8 = c >> 3, cl = c & 7;
    float4 vo;
    {
      int px = g * 4 + 0; int sw = C8 ^ ((px >> 2) & 7);
      vo.x = (float)(*(const f16*)&xs[px * 264 + sw * 8 + cl]);
    }
    {
      int px = g * 4 + 1; int sw = C8 ^ ((px >> 2) & 7);
      vo.y = (float)(*(const f16*)&xs[px * 264 + sw * 8 + cl]);
    }
    {
      int px = g * 4 + 2; int sw = C8 ^ ((px >> 2) & 7);
      vo.z = (float)(*(const f16*)&xs[px * 264 + sw * 8 + cl]);
    }
    {
      int px = g * 4 + 3; int sw = C8 ^ ((px >> 2) & 7);
      vo.w = (float)(*(const f16*)&xs[px * 264 + sw * 8 + cl]);
    }
    *(float4*)(out + ((size_t)(bi * 256 + c)) * HWSZ + hw0 + g * 4) = vo;
  }
}

extern "C" void kernel_launch(void* const* d_in, const int* in_sizes, int n_in,
                              void* d_out, int out_size, void* d_ws, size_t ws_size,
                              hipStream_t stream) {
  const float* noisy = (const float*)d_in[0];
  const float* aux   = (const float*)d_in[1];
  const float* Wmap  = (const float*)d_in[2];
  const float* bmap  = (const float*)d_in[3];
  const float* Wq    = (const float*)d_in[4];
  const float* Wk    = (const float*)d_in[5];
  const float* Wv    = (const float*)d_in[6];
  const float* relh  = (const float*)d_in[7];
  const float* relw  = (const float*)d_in[8];
  float* out = (float*)d_out;

  char* ws = (char*)d_ws;
  u16* naux  = (u16*)(ws);                   // 40,960,000; reused as o16 after k_qkv
  u16* q     = (u16*)(ws + 40960000);        // 40,960,000
  u16* k     = (u16*)(ws + 81920000);        // 40,960,000
  u16* v     = (u16*)(ws + 122880000);       // 40,960,000
  u16* wmapB = (u16*)(ws + 163840000);       // 262,144
  u16* wqB   = (u16*)(ws + 164102144);       // 131,072
  u16* wkB   = (u16*)(ws + 164233216);       // 131,072
  u16* wvB   = (u16*)(ws + 164364288);       // 131,072
  u16* relB  = (u16*)(ws + 164495360);       // 16,384 (end ~164.5 MB)
  u16* o16   = naux;                          // alias: naux fully consumed before k_attn

  k_tw<<<dim3(512, 5), 256, 0, stream>>>(Wmap, Wq, Wk, Wv, relh, relw,
                                         wmapB, wqB, wkB, wvB, relB);
  k_naux<<<dim3(1250, 2), 256, 0, stream>>>(noisy, aux, wmapB, bmap, naux);
  k_qkv<<<dim3(1250, 2), 256, 0, stream>>>(naux, noisy, wqB, wkB, wvB, q, k, v);
  k_attn<<<dim3(1600, 4, 2), 64, 0, stream>>>(q, k, v, relB, o16);
  k_out<<<dim3(625, 2), 256, 0, stream>>>(o16, out);
}

// Round 5
// 522.557 us; speedup vs baseline: 1.2790x; 1.2790x over previous
//
#include <hip/hip_runtime.h>

typedef unsigned short u16;
typedef unsigned int u32;
typedef _Float16 f16;
typedef __attribute__((ext_vector_type(8))) _Float16 half8;
typedef __attribute__((ext_vector_type(4))) float floatx4;

#define HWSZ 40000
#define NB 40

__device__ __forceinline__ u16 f2h(float f) {
  union { f16 h; u16 u; } c; c.h = (f16)f; return c.u;
}

// ---------------- K0: weight fp32 -> fp16 cast + rel table ----------------
__global__ __launch_bounds__(256) void k_tw(
    const float* __restrict__ Wmap, const float* __restrict__ Wq,
    const float* __restrict__ Wk, const float* __restrict__ Wv,
    const float* __restrict__ relh, const float* __restrict__ relw,
    u16* __restrict__ wmapB, u16* __restrict__ wqB,
    u16* __restrict__ wkB, u16* __restrict__ wvB, u16* __restrict__ relB) {
  int which = blockIdx.y;
  int idx = blockIdx.x * 256 + threadIdx.x;
  if (which == 4) {
    if (idx < 8192) {
      int j = idx >> 6, d = idx & 63;
      float val = 0.f;
      if (j < 121) {
        int ky = j / 11, kx = j - ky * 11;
        val = (d < 32) ? relh[ky * 32 + d] : relw[kx * 32 + (d - 32)];
      }
      relB[idx] = f2h(val);
    }
    return;
  }
  const float* src; u16* dst; int n;
  if (which == 0)      { src = Wmap; dst = wmapB; n = 131072; }
  else if (which == 1) { src = Wq;   dst = wqB;   n = 65536; }
  else if (which == 2) { src = Wk;   dst = wkB;   n = 65536; }
  else                 { src = Wv;   dst = wvB;   n = 65536; }
  if (idx < n) dst[idx] = f2h(src[idx]);
}

// ---------------- K1a: n_aux = relu(W_map @ [noisy;aux] + b), f16 MFMA ----------------
// output fp16 pixel-major [b][hw][256]. Output staging aliases xs (LDS 50->33 KB, 4 blk/CU).
__global__ __launch_bounds__(256) void k_naux(
    const float* __restrict__ noisy, const float* __restrict__ aux,
    const u16* __restrict__ wmapB, const float* __restrict__ bmap,
    u16* __restrict__ naux) {
  __shared__ __align__(16) u16 xs[32 * 520];   // input staging; reused as output staging
  int t = threadIdx.x;
  int bi = blockIdx.y;
  int hw0 = blockIdx.x * 32;
  int wave = t >> 6, lane = t & 63;
  int quad = lane >> 4, l16 = lane & 15;

#pragma unroll
  for (int m = 0; m < 16; ++m) {
    int idx = m * 256 + t;
    int ci = idx >> 3, sub = idx & 7;
    const float* src = (ci < 256 ? noisy + (size_t)(bi * 256 + ci) * HWSZ
                                 : aux + (size_t)(bi * 256 + (ci - 256)) * HWSZ) + hw0 + sub * 4;
    float4 vx = *(const float4*)src;
    xs[(sub * 4 + 0) * 520 + ci] = f2h(vx.x);
    xs[(sub * 4 + 1) * 520 + ci] = f2h(vx.y);
    xs[(sub * 4 + 2) * 520 + ci] = f2h(vx.z);
    xs[(sub * 4 + 3) * 520 + ci] = f2h(vx.w);
  }
  __syncthreads();

  floatx4 acc[4][2];
#pragma unroll
  for (int mt = 0; mt < 4; ++mt)
#pragma unroll
    for (int nt = 0; nt < 2; ++nt) acc[mt][nt] = (floatx4){0.f, 0.f, 0.f, 0.f};

  const u16* wbase = wmapB + (size_t)(wave * 64 + l16) * 512 + quad * 8;
#pragma unroll 4
  for (int ks = 0; ks < 16; ++ks) {
    half8 a[4], b[2];
#pragma unroll
    for (int mt = 0; mt < 4; ++mt)
      a[mt] = *(const half8*)(wbase + mt * 16 * 512 + ks * 32);
#pragma unroll
    for (int nt = 0; nt < 2; ++nt)
      b[nt] = *(const half8*)(&xs[(nt * 16 + l16) * 520 + ks * 32 + quad * 8]);
#pragma unroll
    for (int mt = 0; mt < 4; ++mt)
#pragma unroll
      for (int nt = 0; nt < 2; ++nt)
        acc[mt][nt] = __builtin_amdgcn_mfma_f32_16x16x32_f16(a[mt], b[nt], acc[mt][nt], 0, 0, 0);
  }
  __syncthreads();   // all xs reads done -> safe to reuse xs for output staging

#pragma unroll
  for (int mt = 0; mt < 4; ++mt) {
#pragma unroll
    for (int r = 0; r < 4; ++r) {
      int co = wave * 64 + mt * 16 + quad * 4 + r;
      float bv = bmap[co];
#pragma unroll
      for (int nt = 0; nt < 2; ++nt) {
        int px = nt * 16 + l16;
        xs[px * 264 + co] = f2h(fmaxf(acc[mt][nt][r] + bv, 0.f));
      }
    }
  }
  __syncthreads();

#pragma unroll
  for (int m = 0; m < 4; ++m) {
    int idx = m * 256 + t;
    int px = idx >> 5, sub = idx & 31;
    *(uint4*)(naux + ((size_t)bi * HWSZ + hw0 + px) * 256 + sub * 8) =
        *(const uint4*)(&xs[px * 264 + sub * 8]);
  }
}

// ---------------- K1b: q,k from naux; v from noisy — f16 MFMA ----------------
__global__ __launch_bounds__(256) void k_qkv(
    const u16* __restrict__ naux, const float* __restrict__ noisy,
    const u16* __restrict__ wqB, const u16* __restrict__ wkB,
    const u16* __restrict__ wvB,
    u16* __restrict__ q, u16* __restrict__ k, u16* __restrict__ v) {
  __shared__ __align__(16) u16 xs[32 * 264];
  __shared__ __align__(16) u16 os[32 * 264];
  int t = threadIdx.x;
  int bi = blockIdx.y;
  int hw0 = blockIdx.x * 32;
  int wave = t >> 6, lane = t & 63;
  int quad = lane >> 4, l16 = lane & 15;

#pragma unroll
  for (int m = 0; m < 4; ++m) {
    int idx = m * 256 + t;
    int px = idx >> 5, sub = idx & 31;
    *(uint4*)(&xs[px * 264 + sub * 8]) =
        *(const uint4*)(naux + ((size_t)bi * HWSZ + hw0 + px) * 256 + sub * 8);
  }
  __syncthreads();

#pragma unroll 1
  for (int pass = 0; pass < 2; ++pass) {
    const u16* wb = (pass == 0 ? wqB : wkB) + (size_t)(wave * 64 + l16) * 256 + quad * 8;
    floatx4 acc[4][2];
#pragma unroll
    for (int mt = 0; mt < 4; ++mt)
#pragma unroll
      for (int nt = 0; nt < 2; ++nt) acc[mt][nt] = (floatx4){0.f, 0.f, 0.f, 0.f};
#pragma unroll 4
    for (int ks = 0; ks < 8; ++ks) {
      half8 a[4], b[2];
#pragma unroll
      for (int mt = 0; mt < 4; ++mt)
        a[mt] = *(const half8*)(wb + mt * 16 * 256 + ks * 32);
#pragma unroll
      for (int nt = 0; nt < 2; ++nt)
        b[nt] = *(const half8*)(&xs[(nt * 16 + l16) * 264 + ks * 32 + quad * 8]);
#pragma unroll
      for (int mt = 0; mt < 4; ++mt)
#pragma unroll
        for (int nt = 0; nt < 2; ++nt)
          acc[mt][nt] = __builtin_amdgcn_mfma_f32_16x16x32_f16(a[mt], b[nt], acc[mt][nt], 0, 0, 0);
    }
    float scale = pass == 0 ? 0.125f : 1.f;
#pragma unroll
    for (int mt = 0; mt < 4; ++mt)
#pragma unroll
      for (int r = 0; r < 4; ++r) {
        int co = wave * 64 + mt * 16 + quad * 4 + r;
#pragma unroll
        for (int nt = 0; nt < 2; ++nt)
          os[(nt * 16 + l16) * 264 + co] = f2h(acc[mt][nt][r] * scale);
      }
    __syncthreads();
    u16* dst = pass == 0 ? q : k;
#pragma unroll
    for (int m = 0; m < 4; ++m) {
      int idx = m * 256 + t;
      int px = idx >> 5, sub = idx & 31;
      *(uint4*)(dst + ((size_t)bi * HWSZ + hw0 + px) * 256 + sub * 8) =
          *(const uint4*)(&os[px * 264 + sub * 8]);
    }
    __syncthreads();
  }

#pragma unroll
  for (int m = 0; m < 8; ++m) {
    int idx = m * 256 + t;
    int ci = idx >> 3, sub = idx & 7;
    const float* src = noisy + (size_t)(bi * 256 + ci) * HWSZ + hw0 + sub * 4;
    float4 vx = *(const float4*)src;
    xs[(sub * 4 + 0) * 264 + ci] = f2h(vx.x);
    xs[(sub * 4 + 1) * 264 + ci] = f2h(vx.y);
    xs[(sub * 4 + 2) * 264 + ci] = f2h(vx.z);
    xs[(sub * 4 + 3) * 264 + ci] = f2h(vx.w);
  }
  __syncthreads();
  {
    const u16* wb = wvB + (size_t)(wave * 64 + l16) * 256 + quad * 8;
    floatx4 acc[4][2];
#pragma unroll
    for (int mt = 0; mt < 4; ++mt)
#pragma unroll
      for (int nt = 0; nt < 2; ++nt) acc[mt][nt] = (floatx4){0.f, 0.f, 0.f, 0.f};
#pragma unroll 4
    for (int ks = 0; ks < 8; ++ks) {
      half8 a[4], b[2];
#pragma unroll
      for (int mt = 0; mt < 4; ++mt)
        a[mt] = *(const half8*)(wb + mt * 16 * 256 + ks * 32);
#pragma unroll
      for (int nt = 0; nt < 2; ++nt)
        b[nt] = *(const half8*)(&xs[(nt * 16 + l16) * 264 + ks * 32 + quad * 8]);
#pragma unroll
      for (int mt = 0; mt < 4; ++mt)
#pragma unroll
        for (int nt = 0; nt < 2; ++nt)
          acc[mt][nt] = __builtin_amdgcn_mfma_f32_16x16x32_f16(a[mt], b[nt], acc[mt][nt], 0, 0, 0);
    }
#pragma unroll
    for (int mt = 0; mt < 4; ++mt)
#pragma unroll
      for (int r = 0; r < 4; ++r) {
        int co = wave * 64 + mt * 16 + quad * 4 + r;
#pragma unroll
        for (int nt = 0; nt < 2; ++nt)
          os[(nt * 16 + l16) * 264 + co] = f2h(acc[mt][nt][r]);
      }
    __syncthreads();
#pragma unroll
    for (int m = 0; m < 4; ++m) {
      int idx = m * 256 + t;
      int px = idx >> 5, sub = idx & 31;
      *(uint4*)(v + ((size_t)bi * HWSZ + hw0 + px) * 256 + sub * 8) =
          *(const uint4*)(&os[px * 264 + sub * 8]);
    }
  }
}

// ---------------- K2: halo block attention — d-split V, NO-SCRATCH build ----------------
// All loops indexing acc/r1 are FULLY unrolled (runtime-indexed ext_vector arrays
// otherwise go to scratch: that was the hidden 400 MB WRITE_SIZE).
// __launch_bounds__(64, 2): VGPR cap 256 so the compiler doesn't force spills;
// occupancy stays LDS-bound (16 KB -> 10 blocks/CU).
__global__ __launch_bounds__(64, 2) void k_attn(
    const u16* __restrict__ q, const u16* __restrict__ k,
    const u16* __restrict__ v, const u16* __restrict__ relB,
    u16* __restrict__ o16) {
  __shared__ __align__(16) u16 vt[8 * 512];    // one d-half of V^T frags (8 KB)
  __shared__ __align__(16) u16 pf[8 * 512];    // P frags (8 KB)

  int t = threadIdx.x;           // single wave
  int bb = blockIdx.z;
  int head = blockIdx.y;
  int bid = blockIdx.x;
  int sb = (bid & 7) * 200 + (bid >> 3);       // XCD-chunked bijective swizzle
  int by = sb / NB, bx = sb % NB;
  int l16 = t & 15, quad = t >> 4;
  int hi = l16 >> 3, lowl = l16 & 7;

  const size_t hbase = (size_t)bb * HWSZ;
  const int hoff = head * 64;

  // ---- stage V^T half0 (d 0..31) + prefetch half1 (d 32..63) into regs ----
  uint4 r1[8];
#pragma unroll
  for (int it = 0; it < 8; ++it) {
    int idx = it * 64 + t;       // 0..511: j x c8p(4 chunks of d-half)
    int j = idx >> 2, c8p = idx & 3;
    int jc = min(j, 120);
    int ky = jc / 11, kx = jc - ky * 11;
    int y = by * 5 - 3 + ky, x = bx * 5 - 3 + kx;
    bool inb = (j <= 120) && (y >= 0) && (y < 200) && (x >= 0) && (x < 200);
    int yc = min(max(y, 0), 199), xc = min(max(x, 0), 199);
    const u16* vb = v + (hbase + yc * 200 + xc) * 256 + hoff;
    uint4 raw0 = *(const uint4*)(vb + c8p * 8);
    uint4 raw1 = *(const uint4*)(vb + 32 + c8p * 8);
    if (!inb) { raw0 = (uint4){0, 0, 0, 0}; raw1 = (uint4){0, 0, 0, 0}; }
    r1[it] = raw1;
    int frag = (c8p >> 1) * 4 + (j >> 5);
    int tb = ((j >> 3) & 3) * 16 + (c8p & 1) * 8;
    int msk = ((tb >> 3) & 3) << 4;
    int e = j & 7;
    u32 w[4] = {raw0.x, raw0.y, raw0.z, raw0.w};
#pragma unroll
    for (int i = 0; i < 8; ++i) {
      u16 val = (u16)((i & 1) ? (w[i >> 1] >> 16) : (w[i >> 1] & 0xffffu));
      vt[frag * 512 + (((tb + i) * 8) ^ msk) + e] = val;
    }
  }

  // ---- Q a-frags from global ----
  half8 aq[2][2];
#pragma unroll
  for (int mt = 0; mt < 2; ++mt) {
    int i = min(mt * 16 + l16, 24);
    int y = by * 5 + i / 5, x = bx * 5 + i % 5;
    const u16* qb = q + (hbase + y * 200 + x) * 256 + hoff;
#pragma unroll
    for (int ks = 0; ks < 2; ++ks)
      aq[mt][ks] = *(const half8*)(qb + ks * 32 + quad * 8);
  }

  // ---- S = Q.K^T + Q.Rel^T (FULL unroll: acc must stay in VGPRs) ----
  floatx4 acc[2][8];
#pragma unroll
  for (int mt = 0; mt < 2; ++mt)
#pragma unroll
    for (int nt = 0; nt < 8; ++nt) acc[mt][nt] = (floatx4){0.f, 0.f, 0.f, 0.f};

#pragma unroll
  for (int nt = 0; nt < 8; ++nt) {
    int j = nt * 16 + l16;
    int jc = min(j, 120);
    int ky = jc / 11, kx = jc - ky * 11;
    int y = by * 5 - 3 + ky, x = bx * 5 - 3 + kx;
    bool inb = (y >= 0) && (y < 200) && (x >= 0) && (x < 200);
    int yc = min(max(y, 0), 199), xc = min(max(x, 0), 199);
    const u16* kb = k + (hbase + yc * 200 + xc) * 256 + hoff;
    const u16* rb = relB + jc * 64;
#pragma unroll
    for (int ks = 0; ks < 2; ++ks) {
      uint4 raw = *(const uint4*)(kb + ks * 32 + quad * 8);
      if (!inb) raw = (uint4){0, 0, 0, 0};
      union { uint4 u; half8 h; } kc; kc.u = raw;
      half8 rl = *(const half8*)(rb + ks * 32 + quad * 8);
#pragma unroll
      for (int mt = 0; mt < 2; ++mt) {
        acc[mt][nt] = __builtin_amdgcn_mfma_f32_16x16x32_f16(aq[mt][ks], kc.h, acc[mt][nt], 0, 0, 0);
        acc[mt][nt] = __builtin_amdgcn_mfma_f32_16x16x32_f16(aq[mt][ks], rl, acc[mt][nt], 0, 0, 0);
      }
    }
  }
  __syncthreads();  // vt half0 staged

  // ---- softmax in registers + write P frags (swizzled) ----
  float rinv[2][4];
#pragma unroll
  for (int mt = 0; mt < 2; ++mt) {
#pragma unroll
    for (int r = 0; r < 4; ++r) {
      float vmax = acc[mt][0][r];
#pragma unroll
      for (int nt = 1; nt < 7; ++nt) vmax = fmaxf(vmax, acc[mt][nt][r]);
      float x7 = (l16 < 9) ? acc[mt][7][r] : -INFINITY;
      vmax = fmaxf(vmax, x7);
#pragma unroll
      for (int off = 1; off < 16; off <<= 1)
        vmax = fmaxf(vmax, __shfl_xor(vmax, off, 16));
      float es[8], sum = 0.f;
#pragma unroll
      for (int nt = 0; nt < 7; ++nt) { es[nt] = __expf(acc[mt][nt][r] - vmax); sum += es[nt]; }
      es[7] = (l16 < 9) ? __expf(acc[mt][7][r] - vmax) : 0.f;
      sum += es[7];
#pragma unroll
      for (int off = 1; off < 16; off <<= 1)
        sum += __shfl_xor(sum, off, 16);
      rinv[mt][r] = 1.f / sum;
      int arow = quad * 4 + r;
#pragma unroll
      for (int nt = 0; nt < 8; ++nt) {
        int T2 = ((nt & 1) * 2 + hi) * 16 + arow;
        pf[(mt * 4 + (nt >> 1)) * 512 + ((T2 * 8) ^ (((T2 >> 3) & 3) << 4)) + lowl] = f2h(es[nt]);
      }
    }
  }
  __syncthreads();  // pf written

  // ---- O = P.V, d-half 0 (nd 0,1) ----
  int swzr = (t * 8) ^ (((t >> 3) & 3) << 4);
  floatx4 o[2][4];
#pragma unroll
  for (int mt = 0; mt < 2; ++mt)
#pragma unroll
    for (int nd = 0; nd < 4; ++nd) o[mt][nd] = (floatx4){0.f, 0.f, 0.f, 0.f};
#pragma unroll
  for (int ks = 0; ks < 4; ++ks) {
    half8 a[2], b[2];
#pragma unroll
    for (int mt = 0; mt < 2; ++mt)
      a[mt] = *(const half8*)(&pf[(mt * 4 + ks) * 512 + swzr]);
#pragma unroll
    for (int ndl = 0; ndl < 2; ++ndl)
      b[ndl] = *(const half8*)(&vt[(ndl * 4 + ks) * 512 + swzr]);
#pragma unroll
    for (int mt = 0; mt < 2; ++mt)
#pragma unroll
      for (int ndl = 0; ndl < 2; ++ndl)
        o[mt][ndl] = __builtin_amdgcn_mfma_f32_16x16x32_f16(a[mt], b[ndl], o[mt][ndl], 0, 0, 0);
  }
  __syncthreads();  // half0 reads done

  // ---- write V^T half1 from regs (FULL unroll: r1 must stay in VGPRs) ----
#pragma unroll
  for (int it = 0; it < 8; ++it) {
    int idx = it * 64 + t;
    int j = idx >> 2, c8p = idx & 3;
    int frag = (c8p >> 1) * 4 + (j >> 5);
    int tb = ((j >> 3) & 3) * 16 + (c8p & 1) * 8;
    int msk = ((tb >> 3) & 3) << 4;
    int e = j & 7;
    u32 w[4] = {r1[it].x, r1[it].y, r1[it].z, r1[it].w};
#pragma unroll
    for (int i = 0; i < 8; ++i) {
      u16 val = (u16)((i & 1) ? (w[i >> 1] >> 16) : (w[i >> 1] & 0xffffu));
      vt[frag * 512 + (((tb + i) * 8) ^ msk) + e] = val;
    }
  }
  __syncthreads();  // half1 staged

  // ---- O = P.V, d-half 1 (nd 2,3) ----
#pragma unroll
  for (int ks = 0; ks < 4; ++ks) {
    half8 a[2], b[2];
#pragma unroll
    for (int mt = 0; mt < 2; ++mt)
      a[mt] = *(const half8*)(&pf[(mt * 4 + ks) * 512 + swzr]);
#pragma unroll
    for (int ndl = 0; ndl < 2; ++ndl)
      b[ndl] = *(const half8*)(&vt[(ndl * 4 + ks) * 512 + swzr]);
#pragma unroll
    for (int mt = 0; mt < 2; ++mt)
#pragma unroll
      for (int ndl = 0; ndl < 2; ++ndl)
        o[mt][2 + ndl] = __builtin_amdgcn_mfma_f32_16x16x32_f16(a[mt], b[ndl], o[mt][2 + ndl], 0, 0, 0);
  }

  // ---- epilogue: scale by 1/sum, store fp16 pixel-major (32B segments) ----
#pragma unroll
  for (int mt = 0; mt < 2; ++mt) {
#pragma unroll
    for (int r = 0; r < 4; ++r) {
      int i = mt * 16 + quad * 4 + r;
      if (i < 25) {
        int y = by * 5 + i / 5, x = bx * 5 + i % 5;
        float rs = rinv[mt][r];
        u16* ob = o16 + (hbase + y * 200 + x) * 256 + hoff;
#pragma unroll
        for (int nd = 0; nd < 4; ++nd)
          ob[nd * 16 + l16] = f2h(o[mt][nd][r] * rs);
      }
    }
  }
}

// ---------------- K3: transpose o16 [b][hw][256] f16 -> out [b][c][h][w] f32 ----------------
__global__ __launch_bounds__(256) void k_out(
    const u16* __restrict__ o16, float* __restrict__ out) {
  __shared__ __align__(16) u16 xs[64 * 264];
  int t = threadIdx.x;
  int bi = blockIdx.y;
  int hw0 = blockIdx.x * 64;
#pragma unroll
  for (int m = 0; m < 8; ++m) {
    int idx = m * 256 + t;
    int px = idx >> 5, sub = idx & 31;
    int sw = sub ^ ((px >> 2) & 7);
    *(uint4*)(&xs[px * 264 + sw * 8]) =
        *(const uint4*)(o16 + ((size_t)bi * HWSZ + hw0 + px) * 256 + sub * 8);
  }
  __syncthreads();
#pragma unroll
  for (int m = 0; m < 16; ++m) {
    int idx = m * 256 + t;
    int c = idx >> 4, g = idx & 15;
    int C8 = c >> 3, cl = c & 7;
    float4 vo;
    {
      int px = g * 4 + 0; int sw = C8 ^ ((px >> 2) & 7);
      vo.x = (float)(*(const f16*)&xs[px * 264 + sw * 8 + cl]);
    }
    {
      int px = g * 4 + 1; int sw = C8 ^ ((px >> 2) & 7);
      vo.y = (float)(*(const f16*)&xs[px * 264 + sw * 8 + cl]);
    }
    {
      int px = g * 4 + 2; int sw = C8 ^ ((px >> 2) & 7);
      vo.z = (float)(*(const f16*)&xs[px * 264 + sw * 8 + cl]);
    }
    {
      int px = g * 4 + 3; int sw = C8 ^ ((px >> 2) & 7);
      vo.w = (float)(*(const f16*)&xs[px * 264 + sw * 8 + cl]);
    }
    *(float4*)(out + ((size_t)(bi * 256 + c)) * HWSZ + hw0 + g * 4) = vo;
  }
}

extern "C" void kernel_launch(void* const* d_in, const int* in_sizes, int n_in,
                              void* d_out, int out_size, void* d_ws, size_t ws_size,
                              hipStream_t stream) {
  const float* noisy = (const float*)d_in[0];
  const float* aux   = (const float*)d_in[1];
  const float* Wmap  = (const float*)d_in[2];
  const float* bmap  = (const float*)d_in[3];
  const float* Wq    = (const float*)d_in[4];
  const float* Wk    = (const float*)d_in[5];
  const float* Wv    = (const float*)d_in[6];
  const float* relh  = (const float*)d_in[7];
  const float* relw  = (const float*)d_in[8];
  float* out = (float*)d_out;

  char* ws = (char*)d_ws;
  u16* naux  = (u16*)(ws);                   // 40,960,000; reused as o16 after k_qkv
  u16* q     = (u16*)(ws + 40960000);        // 40,960,000
  u16* k     = (u16*)(ws + 81920000);        // 40,960,000
  u16* v     = (u16*)(ws + 122880000);       // 40,960,000
  u16* wmapB = (u16*)(ws + 163840000);       // 262,144
  u16* wqB   = (u16*)(ws + 164102144);       // 131,072
  u16* wkB   = (u16*)(ws + 164233216);       // 131,072
  u16* wvB   = (u16*)(ws + 164364288);       // 131,072
  u16* relB  = (u16*)(ws + 164495360);       // 16,384 (end ~164.5 MB)
  u16* o16   = naux;                          // alias: naux fully consumed before k_attn

  k_tw<<<dim3(512, 5), 256, 0, stream>>>(Wmap, Wq, Wk, Wv, relh, relw,
                                         wmapB, wqB, wkB, wvB, relB);
  k_naux<<<dim3(1250, 2), 256, 0, stream>>>(noisy, aux, wmapB, bmap, naux);
  k_qkv<<<dim3(1250, 2), 256, 0, stream>>>(naux, noisy, wqB, wkB, wvB, q, k, v);
  k_attn<<<dim3(1600, 4, 2), 64, 0, stream>>>(q, k, v, relB, o16);
  k_out<<<dim3(625, 2), 256, 0, stream>>>(o16, out);
}

// Round 6
// 518.473 us; speedup vs baseline: 1.2891x; 1.0079x over previous
//
#include <hip/hip_runtime.h>

typedef unsigned short u16;
typedef unsigned int u32;
typedef unsigned long long u64;
typedef _Float16 f16;
typedef __attribute__((ext_vector_type(8))) _Float16 half8;
typedef __attribute__((ext_vector_type(4))) float floatx4;

#define HWSZ 40000
#define NB 40

__device__ __forceinline__ u16 f2h(float f) {
  union { f16 h; u16 u; } c; c.h = (f16)f; return c.u;
}

// Pack 4 f32 -> u64 of 4 f16
__device__ __forceinline__ u64 pk4(float a, float b, float c, float d) {
  return (u64)f2h(a) | ((u64)f2h(b) << 16) | ((u64)f2h(c) << 32) | ((u64)f2h(d) << 48);
}

// 4x4 quad-transpose across lanes (quad = lane>>4) + coalesced 32B store.
// In: x[m] at lane(quad g) = chs [base + m*16 + g*4 .. +3] (4 f16 packed).
// Out: lane g stores chs [base + g*16 .. +15] at p + g*16 (two uint4 = 32B).
__device__ __forceinline__ void tr_store(u64 x0, u64 x1, u64 x2, u64 x3,
                                         int quad, u16* p) {
  u64 s, a0, a1, a2, a3, b0, b1, b2, b3;
  s = __shfl_xor(x1, 16); a0 = ((quad & 1) == 0) ? x0 : s;
  s = __shfl_xor(x0, 16); a1 = ((quad & 1) == 1) ? x1 : s;
  s = __shfl_xor(x3, 16); a2 = ((quad & 1) == 0) ? x2 : s;
  s = __shfl_xor(x2, 16); a3 = ((quad & 1) == 1) ? x3 : s;
  s = __shfl_xor(a2, 32); b0 = ((quad & 2) == 0) ? a0 : s;
  s = __shfl_xor(a3, 32); b1 = ((quad & 2) == 0) ? a1 : s;
  s = __shfl_xor(a0, 32); b2 = ((quad & 2) == 2) ? a2 : s;
  s = __shfl_xor(a1, 32); b3 = ((quad & 2) == 2) ? a3 : s;
  union { u64 q[2]; uint4 v; } lo, hi;
  lo.q[0] = b0; lo.q[1] = b1;
  hi.q[0] = b2; hi.q[1] = b3;
  *(uint4*)(p + quad * 16) = lo.v;
  *(uint4*)(p + quad * 16 + 8) = hi.v;
}

// ---------------- K0: weight fp32 -> fp16 cast + rel table ----------------
__global__ __launch_bounds__(256) void k_tw(
    const float* __restrict__ Wmap, const float* __restrict__ Wq,
    const float* __restrict__ Wk, const float* __restrict__ Wv,
    const float* __restrict__ relh, const float* __restrict__ relw,
    u16* __restrict__ wmapB, u16* __restrict__ wqB,
    u16* __restrict__ wkB, u16* __restrict__ wvB, u16* __restrict__ relB) {
  int which = blockIdx.y;
  int idx = blockIdx.x * 256 + threadIdx.x;
  if (which == 4) {
    if (idx < 8192) {
      int j = idx >> 6, d = idx & 63;
      float val = 0.f;
      if (j < 121) {
        int ky = j / 11, kx = j - ky * 11;
        val = (d < 32) ? relh[ky * 32 + d] : relw[kx * 32 + (d - 32)];
      }
      relB[idx] = f2h(val);
    }
    return;
  }
  const float* src; u16* dst; int n;
  if (which == 0)      { src = Wmap; dst = wmapB; n = 131072; }
  else if (which == 1) { src = Wq;   dst = wqB;   n = 65536; }
  else if (which == 2) { src = Wk;   dst = wkB;   n = 65536; }
  else                 { src = Wv;   dst = wvB;   n = 65536; }
  if (idx < n) dst[idx] = f2h(src[idx]);
}

// ---------------- K1a: n_aux = relu(W_map @ [noisy;aux] + b) ----------------
// Output via in-register quad-transpose + coalesced stores (no os, no extra barriers).
__global__ __launch_bounds__(256) void k_naux(
    const float* __restrict__ noisy, const float* __restrict__ aux,
    const u16* __restrict__ wmapB, const float* __restrict__ bmap,
    u16* __restrict__ naux) {
  __shared__ __align__(16) u16 xs[32 * 520];   // input staging only (33.3 KB)
  int t = threadIdx.x;
  int bi = blockIdx.y;
  int hw0 = blockIdx.x * 32;
  int wave = t >> 6, lane = t & 63;
  int quad = lane >> 4, l16 = lane & 15;

#pragma unroll
  for (int m = 0; m < 16; ++m) {
    int idx = m * 256 + t;
    int ci = idx >> 3, sub = idx & 7;
    const float* src = (ci < 256 ? noisy + (size_t)(bi * 256 + ci) * HWSZ
                                 : aux + (size_t)(bi * 256 + (ci - 256)) * HWSZ) + hw0 + sub * 4;
    float4 vx = *(const float4*)src;
    xs[(sub * 4 + 0) * 520 + ci] = f2h(vx.x);
    xs[(sub * 4 + 1) * 520 + ci] = f2h(vx.y);
    xs[(sub * 4 + 2) * 520 + ci] = f2h(vx.z);
    xs[(sub * 4 + 3) * 520 + ci] = f2h(vx.w);
  }
  __syncthreads();

  floatx4 acc[4][2];
#pragma unroll
  for (int mt = 0; mt < 4; ++mt)
#pragma unroll
    for (int nt = 0; nt < 2; ++nt) acc[mt][nt] = (floatx4){0.f, 0.f, 0.f, 0.f};

  const u16* wbase = wmapB + (size_t)(wave * 64 + l16) * 512 + quad * 8;
#pragma unroll 4
  for (int ks = 0; ks < 16; ++ks) {
    half8 a[4], b[2];
#pragma unroll
    for (int mt = 0; mt < 4; ++mt)
      a[mt] = *(const half8*)(wbase + mt * 16 * 512 + ks * 32);
#pragma unroll
    for (int nt = 0; nt < 2; ++nt)
      b[nt] = *(const half8*)(&xs[(nt * 16 + l16) * 520 + ks * 32 + quad * 8]);
#pragma unroll
    for (int mt = 0; mt < 4; ++mt)
#pragma unroll
      for (int nt = 0; nt < 2; ++nt)
        acc[mt][nt] = __builtin_amdgcn_mfma_f32_16x16x32_f16(a[mt], b[nt], acc[mt][nt], 0, 0, 0);
  }

  // bias + relu in regs, quad-transpose, coalesced store
  float4 bv[4];
#pragma unroll
  for (int mt = 0; mt < 4; ++mt)
    bv[mt] = *(const float4*)(bmap + wave * 64 + mt * 16 + quad * 4);
#pragma unroll
  for (int nt = 0; nt < 2; ++nt) {
    u64 x[4];
#pragma unroll
    for (int mt = 0; mt < 4; ++mt)
      x[mt] = pk4(fmaxf(acc[mt][nt][0] + bv[mt].x, 0.f),
                  fmaxf(acc[mt][nt][1] + bv[mt].y, 0.f),
                  fmaxf(acc[mt][nt][2] + bv[mt].z, 0.f),
                  fmaxf(acc[mt][nt][3] + bv[mt].w, 0.f));
    u16* p = naux + ((size_t)bi * HWSZ + hw0 + nt * 16 + l16) * 256 + wave * 64;
    tr_store(x[0], x[1], x[2], x[3], quad, p);
  }
}

// ---------------- K1b: q,k from naux; v from noisy ----------------
// os removed: outputs via quad-transpose direct stores. 3 barriers (was 6).
__global__ __launch_bounds__(256, 4) void k_qkv(
    const u16* __restrict__ naux, const float* __restrict__ noisy,
    const u16* __restrict__ wqB, const u16* __restrict__ wkB,
    const u16* __restrict__ wvB,
    u16* __restrict__ q, u16* __restrict__ k, u16* __restrict__ v) {
  __shared__ __align__(16) u16 xs[32 * 264];   // 16.9 KB
  int t = threadIdx.x;
  int bi = blockIdx.y;
  int hw0 = blockIdx.x * 32;
  int wave = t >> 6, lane = t & 63;
  int quad = lane >> 4, l16 = lane & 15;

#pragma unroll
  for (int m = 0; m < 4; ++m) {
    int idx = m * 256 + t;
    int px = idx >> 5, sub = idx & 31;
    *(uint4*)(&xs[px * 264 + sub * 8]) =
        *(const uint4*)(naux + ((size_t)bi * HWSZ + hw0 + px) * 256 + sub * 8);
  }
  __syncthreads();

  // q and k passes both read the untouched xs
#pragma unroll 1
  for (int pass = 0; pass < 2; ++pass) {
    const u16* wb = (pass == 0 ? wqB : wkB) + (size_t)(wave * 64 + l16) * 256 + quad * 8;
    floatx4 acc[4][2];
#pragma unroll
    for (int mt = 0; mt < 4; ++mt)
#pragma unroll
      for (int nt = 0; nt < 2; ++nt) acc[mt][nt] = (floatx4){0.f, 0.f, 0.f, 0.f};
#pragma unroll 4
    for (int ks = 0; ks < 8; ++ks) {
      half8 a[4], b[2];
#pragma unroll
      for (int mt = 0; mt < 4; ++mt)
        a[mt] = *(const half8*)(wb + mt * 16 * 256 + ks * 32);
#pragma unroll
      for (int nt = 0; nt < 2; ++nt)
        b[nt] = *(const half8*)(&xs[(nt * 16 + l16) * 264 + ks * 32 + quad * 8]);
#pragma unroll
      for (int mt = 0; mt < 4; ++mt)
#pragma unroll
        for (int nt = 0; nt < 2; ++nt)
          acc[mt][nt] = __builtin_amdgcn_mfma_f32_16x16x32_f16(a[mt], b[nt], acc[mt][nt], 0, 0, 0);
    }
    float scale = pass == 0 ? 0.125f : 1.f;
    u16* dst = pass == 0 ? q : k;
#pragma unroll
    for (int nt = 0; nt < 2; ++nt) {
      u64 x[4];
#pragma unroll
      for (int mt = 0; mt < 4; ++mt)
        x[mt] = pk4(acc[mt][nt][0] * scale, acc[mt][nt][1] * scale,
                    acc[mt][nt][2] * scale, acc[mt][nt][3] * scale);
      u16* p = dst + ((size_t)bi * HWSZ + hw0 + nt * 16 + l16) * 256 + wave * 64;
      tr_store(x[0], x[1], x[2], x[3], quad, p);
    }
  }
  __syncthreads();   // all xs (naux) reads done

  // restage xs with noisy f16 for the v pass
#pragma unroll
  for (int m = 0; m < 8; ++m) {
    int idx = m * 256 + t;
    int ci = idx >> 3, sub = idx & 7;
    const float* src = noisy + (size_t)(bi * 256 + ci) * HWSZ + hw0 + sub * 4;
    float4 vx = *(const float4*)src;
    xs[(sub * 4 + 0) * 264 + ci] = f2h(vx.x);
    xs[(sub * 4 + 1) * 264 + ci] = f2h(vx.y);
    xs[(sub * 4 + 2) * 264 + ci] = f2h(vx.z);
    xs[(sub * 4 + 3) * 264 + ci] = f2h(vx.w);
  }
  __syncthreads();
  {
    const u16* wb = wvB + (size_t)(wave * 64 + l16) * 256 + quad * 8;
    floatx4 acc[4][2];
#pragma unroll
    for (int mt = 0; mt < 4; ++mt)
#pragma unroll
      for (int nt = 0; nt < 2; ++nt) acc[mt][nt] = (floatx4){0.f, 0.f, 0.f, 0.f};
#pragma unroll 4
    for (int ks = 0; ks < 8; ++ks) {
      half8 a[4], b[2];
#pragma unroll
      for (int mt = 0; mt < 4; ++mt)
        a[mt] = *(const half8*)(wb + mt * 16 * 256 + ks * 32);
#pragma unroll
      for (int nt = 0; nt < 2; ++nt)
        b[nt] = *(const half8*)(&xs[(nt * 16 + l16) * 264 + ks * 32 + quad * 8]);
#pragma unroll
      for (int mt = 0; mt < 4; ++mt)
#pragma unroll
        for (int nt = 0; nt < 2; ++nt)
          acc[mt][nt] = __builtin_amdgcn_mfma_f32_16x16x32_f16(a[mt], b[nt], acc[mt][nt], 0, 0, 0);
    }
#pragma unroll
    for (int nt = 0; nt < 2; ++nt) {
      u64 x[4];
#pragma unroll
      for (int mt = 0; mt < 4; ++mt)
        x[mt] = pk4(acc[mt][nt][0], acc[mt][nt][1], acc[mt][nt][2], acc[mt][nt][3]);
      u16* p = v + ((size_t)bi * HWSZ + hw0 + nt * 16 + l16) * 256 + wave * 64;
      tr_store(x[0], x[1], x[2], x[3], quad, p);
    }
  }
}

// ---------------- K2: halo block attention — d-split V, no-scratch ----------------
__global__ __launch_bounds__(64, 2) void k_attn(
    const u16* __restrict__ q, const u16* __restrict__ k,
    const u16* __restrict__ v, const u16* __restrict__ relB,
    u16* __restrict__ o16) {
  __shared__ __align__(16) u16 vt[8 * 512];    // one d-half of V^T frags (8 KB)
  __shared__ __align__(16) u16 pf[8 * 512];    // P frags (8 KB)

  int t = threadIdx.x;           // single wave
  int bb = blockIdx.z;
  int head = blockIdx.y;
  int bid = blockIdx.x;
  int sb = (bid & 7) * 200 + (bid >> 3);       // XCD-chunked bijective swizzle
  int by = sb / NB, bx = sb % NB;
  int l16 = t & 15, quad = t >> 4;
  int hi = l16 >> 3, lowl = l16 & 7;

  const size_t hbase = (size_t)bb * HWSZ;
  const int hoff = head * 64;

  // ---- stage V^T half0 (d 0..31) + prefetch half1 (d 32..63) into regs ----
  uint4 r1[8];
#pragma unroll
  for (int it = 0; it < 8; ++it) {
    int idx = it * 64 + t;       // 0..511: j x c8p(4 chunks of d-half)
    int j = idx >> 2, c8p = idx & 3;
    int jc = min(j, 120);
    int ky = jc / 11, kx = jc - ky * 11;
    int y = by * 5 - 3 + ky, x = bx * 5 - 3 + kx;
    bool inb = (j <= 120) && (y >= 0) && (y < 200) && (x >= 0) && (x < 200);
    int yc = min(max(y, 0), 199), xc = min(max(x, 0), 199);
    const u16* vb = v + (hbase + yc * 200 + xc) * 256 + hoff;
    uint4 raw0 = *(const uint4*)(vb + c8p * 8);
    uint4 raw1 = *(const uint4*)(vb + 32 + c8p * 8);
    if (!inb) { raw0 = (uint4){0, 0, 0, 0}; raw1 = (uint4){0, 0, 0, 0}; }
    r1[it] = raw1;
    int frag = (c8p >> 1) * 4 + (j >> 5);
    int tb = ((j >> 3) & 3) * 16 + (c8p & 1) * 8;
    int msk = ((tb >> 3) & 3) << 4;
    int e = j & 7;
    u32 w[4] = {raw0.x, raw0.y, raw0.z, raw0.w};
#pragma unroll
    for (int i = 0; i < 8; ++i) {
      u16 val = (u16)((i & 1) ? (w[i >> 1] >> 16) : (w[i >> 1] & 0xffffu));
      vt[frag * 512 + (((tb + i) * 8) ^ msk) + e] = val;
    }
  }

  // ---- Q a-frags from global ----
  half8 aq[2][2];
#pragma unroll
  for (int mt = 0; mt < 2; ++mt) {
    int i = min(mt * 16 + l16, 24);
    int y = by * 5 + i / 5, x = bx * 5 + i % 5;
    const u16* qb = q + (hbase + y * 200 + x) * 256 + hoff;
#pragma unroll
    for (int ks = 0; ks < 2; ++ks)
      aq[mt][ks] = *(const half8*)(qb + ks * 32 + quad * 8);
  }

  // ---- S = Q.K^T + Q.Rel^T (FULL unroll: acc must stay in VGPRs) ----
  floatx4 acc[2][8];
#pragma unroll
  for (int mt = 0; mt < 2; ++mt)
#pragma unroll
    for (int nt = 0; nt < 8; ++nt) acc[mt][nt] = (floatx4){0.f, 0.f, 0.f, 0.f};

#pragma unroll
  for (int nt = 0; nt < 8; ++nt) {
    int j = nt * 16 + l16;
    int jc = min(j, 120);
    int ky = jc / 11, kx = jc - ky * 11;
    int y = by * 5 - 3 + ky, x = bx * 5 - 3 + kx;
    bool inb = (y >= 0) && (y < 200) && (x >= 0) && (x < 200);
    int yc = min(max(y, 0), 199), xc = min(max(x, 0), 199);
    const u16* kb = k + (hbase + yc * 200 + xc) * 256 + hoff;
    const u16* rb = relB + jc * 64;
#pragma unroll
    for (int ks = 0; ks < 2; ++ks) {
      uint4 raw = *(const uint4*)(kb + ks * 32 + quad * 8);
      if (!inb) raw = (uint4){0, 0, 0, 0};
      union { uint4 u; half8 h; } kc; kc.u = raw;
      half8 rl = *(const half8*)(rb + ks * 32 + quad * 8);
#pragma unroll
      for (int mt = 0; mt < 2; ++mt) {
        acc[mt][nt] = __builtin_amdgcn_mfma_f32_16x16x32_f16(aq[mt][ks], kc.h, acc[mt][nt], 0, 0, 0);
        acc[mt][nt] = __builtin_amdgcn_mfma_f32_16x16x32_f16(aq[mt][ks], rl, acc[mt][nt], 0, 0, 0);
      }
    }
  }
  __syncthreads();  // vt half0 staged

  // ---- softmax in registers + write P frags (swizzled) ----
  float rinv[2][4];
#pragma unroll
  for (int mt = 0; mt < 2; ++mt) {
#pragma unroll
    for (int r = 0; r < 4; ++r) {
      float vmax = acc[mt][0][r];
#pragma unroll
      for (int nt = 1; nt < 7; ++nt) vmax = fmaxf(vmax, acc[mt][nt][r]);
      float x7 = (l16 < 9) ? acc[mt][7][r] : -INFINITY;
      vmax = fmaxf(vmax, x7);
#pragma unroll
      for (int off = 1; off < 16; off <<= 1)
        vmax = fmaxf(vmax, __shfl_xor(vmax, off, 16));
      float es[8], sum = 0.f;
#pragma unroll
      for (int nt = 0; nt < 7; ++nt) { es[nt] = __expf(acc[mt][nt][r] - vmax); sum += es[nt]; }
      es[7] = (l16 < 9) ? __expf(acc[mt][7][r] - vmax) : 0.f;
      sum += es[7];
#pragma unroll
      for (int off = 1; off < 16; off <<= 1)
        sum += __shfl_xor(sum, off, 16);
      rinv[mt][r] = 1.f / sum;
      int arow = quad * 4 + r;
#pragma unroll
      for (int nt = 0; nt < 8; ++nt) {
        int T2 = ((nt & 1) * 2 + hi) * 16 + arow;
        pf[(mt * 4 + (nt >> 1)) * 512 + ((T2 * 8) ^ (((T2 >> 3) & 3) << 4)) + lowl] = f2h(es[nt]);
      }
    }
  }
  __syncthreads();  // pf written

  // ---- O = P.V, d-half 0 (nd 0,1) ----
  int swzr = (t * 8) ^ (((t >> 3) & 3) << 4);
  floatx4 o[2][4];
#pragma unroll
  for (int mt = 0; mt < 2; ++mt)
#pragma unroll
    for (int nd = 0; nd < 4; ++nd) o[mt][nd] = (floatx4){0.f, 0.f, 0.f, 0.f};
#pragma unroll
  for (int ks = 0; ks < 4; ++ks) {
    half8 a[2], b[2];
#pragma unroll
    for (int mt = 0; mt < 2; ++mt)
      a[mt] = *(const half8*)(&pf[(mt * 4 + ks) * 512 + swzr]);
#pragma unroll
    for (int ndl = 0; ndl < 2; ++ndl)
      b[ndl] = *(const half8*)(&vt[(ndl * 4 + ks) * 512 + swzr]);
#pragma unroll
    for (int mt = 0; mt < 2; ++mt)
#pragma unroll
      for (int ndl = 0; ndl < 2; ++ndl)
        o[mt][ndl] = __builtin_amdgcn_mfma_f32_16x16x32_f16(a[mt], b[ndl], o[mt][ndl], 0, 0, 0);
  }
  __syncthreads();  // half0 reads done

  // ---- write V^T half1 from regs (FULL unroll: r1 must stay in VGPRs) ----
#pragma unroll
  for (int it = 0; it < 8; ++it) {
    int idx = it * 64 + t;
    int j = idx >> 2, c8p = idx & 3;
    int frag = (c8p >> 1) * 4 + (j >> 5);
    int tb = ((j >> 3) & 3) * 16 + (c8p & 1) * 8;
    int msk = ((tb >> 3) & 3) << 4;
    int e = j & 7;
    u32 w[4] = {r1[it].x, r1[it].y, r1[it].z, r1[it].w};
#pragma unroll
    for (int i = 0; i < 8; ++i) {
      u16 val = (u16)((i & 1) ? (w[i >> 1] >> 16) : (w[i >> 1] & 0xffffu));
      vt[frag * 512 + (((tb + i) * 8) ^ msk) + e] = val;
    }
  }
  __syncthreads();  // half1 staged

  // ---- O = P.V, d-half 1 (nd 2,3) ----
#pragma unroll
  for (int ks = 0; ks < 4; ++ks) {
    half8 a[2], b[2];
#pragma unroll
    for (int mt = 0; mt < 2; ++mt)
      a[mt] = *(const half8*)(&pf[(mt * 4 + ks) * 512 + swzr]);
#pragma unroll
    for (int ndl = 0; ndl < 2; ++ndl)
      b[ndl] = *(const half8*)(&vt[(ndl * 4 + ks) * 512 + swzr]);
#pragma unroll
    for (int mt = 0; mt < 2; ++mt)
#pragma unroll
      for (int ndl = 0; ndl < 2; ++ndl)
        o[mt][2 + ndl] = __builtin_amdgcn_mfma_f32_16x16x32_f16(a[mt], b[ndl], o[mt][2 + ndl], 0, 0, 0);
  }

  // ---- epilogue: scale by 1/sum, store fp16 pixel-major (32B segments) ----
#pragma unroll
  for (int mt = 0; mt < 2; ++mt) {
#pragma unroll
    for (int r = 0; r < 4; ++r) {
      int i = mt * 16 + quad * 4 + r;
      if (i < 25) {
        int y = by * 5 + i / 5, x = bx * 5 + i % 5;
        float rs = rinv[mt][r];
        u16* ob = o16 + (hbase + y * 200 + x) * 256 + hoff;
#pragma unroll
        for (int nd = 0; nd < 4; ++nd)
          ob[nd * 16 + l16] = f2h(o[mt][nd][r] * rs);
      }
    }
  }
}

// ---------------- K3: transpose o16 [b][hw][256] f16 -> out [b][c][h][w] f32 ----------------
__global__ __launch_bounds__(256) void k_out(
    const u16* __restrict__ o16, float* __restrict__ out) {
  __shared__ __align__(16) u16 xs[64 * 264];
  int t = threadIdx.x;
  int bi = blockIdx.y;
  int hw0 = blockIdx.x * 64;
#pragma unroll
  for (int m = 0; m < 8; ++m) {
    int idx = m * 256 + t;
    int px = idx >> 5, sub = idx & 31;
    int sw = sub ^ ((px >> 2) & 7);
    *(uint4*)(&xs[px * 264 + sw * 8]) =
        *(const uint4*)(o16 + ((size_t)bi * HWSZ + hw0 + px) * 256 + sub * 8);
  }
  __syncthreads();
#pragma unroll
  for (int m = 0; m < 16; ++m) {
    int idx = m * 256 + t;
    int c = idx >> 4, g = idx & 15;
    int C8 = c >> 3, cl = c & 7;
    float4 vo;
    {
      int px = g * 4 + 0; int sw = C8 ^ ((px >> 2) & 7);
      vo.x = (float)(*(const f16*)&xs[px * 264 + sw * 8 + cl]);
    }
    {
      int px = g * 4 + 1; int sw = C8 ^ ((px >> 2) & 7);
      vo.y = (float)(*(const f16*)&xs[px * 264 + sw * 8 + cl]);
    }
    {
      int px = g * 4 + 2; int sw = C8 ^ ((px >> 2) & 7);
      vo.z = (float)(*(const f16*)&xs[px * 264 + sw * 8 + cl]);
    }
    {
      int px = g * 4 + 3; int sw = C8 ^ ((px >> 2) & 7);
      vo.w = (float)(*(const f16*)&xs[px * 264 + sw * 8 + cl]);
    }
    *(float4*)(out + ((size_t)(bi * 256 + c)) * HWSZ + hw0 + g * 4) = vo;
  }
}

extern "C" void kernel_launch(void* const* d_in, const int* in_sizes, int n_in,
                              void* d_out, int out_size, void* d_ws, size_t ws_size,
                              hipStream_t stream) {
  const float* noisy = (const float*)d_in[0];
  const float* aux   = (const float*)d_in[1];
  const float* Wmap  = (const float*)d_in[2];
  const float* bmap  = (const float*)d_in[3];
  const float* Wq    = (const float*)d_in[4];
  const float* Wk    = (const float*)d_in[5];
  const float* Wv    = (const float*)d_in[6];
  const float* relh  = (const float*)d_in[7];
  const float* relw  = (const float*)d_in[8];
  float* out = (float*)d_out;

  char* ws = (char*)d_ws;
  u16* naux  = (u16*)(ws);                   // 40,960,000; reused as o16 after k_qkv
  u16* q     = (u16*)(ws + 40960000);        // 40,960,000
  u16* k     = (u16*)(ws + 81920000);        // 40,960,000
  u16* v     = (u16*)(ws + 122880000);       // 40,960,000
  u16* wmapB = (u16*)(ws + 163840000);       // 262,144
  u16* wqB   = (u16*)(ws + 164102144);       // 131,072
  u16* wkB   = (u16*)(ws + 164233216);       // 131,072
  u16* wvB   = (u16*)(ws + 164364288);       // 131,072
  u16* relB  = (u16*)(ws + 164495360);       // 16,384 (end ~164.5 MB)
  u16* o16   = naux;                          // alias: naux fully consumed before k_attn

  k_tw<<<dim3(512, 5), 256, 0, stream>>>(Wmap, Wq, Wk, Wv, relh, relw,
                                         wmapB, wqB, wkB, wvB, relB);
  k_naux<<<dim3(1250, 2), 256, 0, stream>>>(noisy, aux, wmapB, bmap, naux);
  k_qkv<<<dim3(1250, 2), 256, 0, stream>>>(naux, noisy, wqB, wkB, wvB, q, k, v);
  k_attn<<<dim3(1600, 4, 2), 64, 0, stream>>>(q, k, v, relB, o16);
  k_out<<<dim3(625, 2), 256, 0, stream>>>(o16, out);
}